// Round 9
// baseline (827.689 us; speedup 1.0000x reference)
//
#include <hip/hip_runtime.h>
#include <math.h>

#define L_LEN 4096
#define DEV __device__ __forceinline__

typedef __attribute__((ext_vector_type(8))) _Float16 f16x8;
typedef __attribute__((ext_vector_type(4))) float   f32x4;

DEV float silu_f(float x) { return x / (1.f + expf(-x)); }
DEV float sigm_f(float x) { return 1.f / (1.f + expf(-x)); }

DEV void gload16(const void* g, void* l) {
    __builtin_amdgcn_global_load_lds(
        (const __attribute__((address_space(1))) void*)g,
        (__attribute__((address_space(3))) void*)l, 16, 0, 0);
}

// ============================================================================
// conv1: CIN=1, K=5, pad=2 (fp32 direct; writes fp16 channels-last)
// ============================================================================
__global__ __launch_bounds__(256) void conv1_k(
    const float* __restrict__ x, const float* __restrict__ W,
    const float* __restrict__ bias, const float* __restrict__ bnp,
    _Float16* __restrict__ out)
{
    __shared__ float sw[64 * 5];
    __shared__ float ssc[64], ssh[64];
    const int tid = threadIdx.x;
    if (tid < 64) {
        float g = bnp[tid], be = bnp[64 + tid], mn = bnp[128 + tid], vr = bnp[192 + tid];
        float sc = g * rsqrtf(vr + 1e-5f);
        ssc[tid] = sc;
        ssh[tid] = fmaf(bias[tid] - mn, sc, be);
    }
    for (int i = tid; i < 320; i += 256) sw[i] = W[i];
    __syncthreads();

    const int b = blockIdx.y;
    const int l = blockIdx.x * 64 + (tid >> 2);
    const int cq = (tid & 3) * 16;

    float win[5];
#pragma unroll
    for (int k = 0; k < 5; ++k) {
        int ix = l + k - 2;
        win[k] = (ix >= 0 && ix < L_LEN) ? x[(size_t)b * L_LEN + ix] : 0.f;
    }
    __align__(16) _Float16 vv[16];
#pragma unroll
    for (int j = 0; j < 16; ++j) {
        const int co = cq + j;
        float z = 0.f;
#pragma unroll
        for (int k = 0; k < 5; ++k) z = fmaf(sw[co * 5 + k], win[k], z);
        z = fmaf(z, ssc[co], ssh[co]);
        vv[j] = (_Float16)silu_f(z);
    }
    const size_t o = ((size_t)b * L_LEN + l) * 64 + cq;
    *(int4*)(out + o)     = *(const int4*)(vv);
    *(int4*)(out + o + 8) = *(const int4*)(vv + 8);
}

// ============================================================================
// weight prep -> fragment-order fp16 split: [s][t][n][pl][lane][8]
// ============================================================================
template <int CIN, int COUT, int K>
__global__ void prep_w_k(const float* __restrict__ W, _Float16* __restrict__ wf)
{
    constexpr int NTILE = COUT / 16;
    const int i = blockIdx.x * 256 + threadIdx.x;
    const int total = (CIN / 32) * K * NTILE * 2 * 64;
    if (i >= total) return;
    const int lane = i & 63;
    int r = i >> 6;
    const int pl = r & 1;  r >>= 1;
    const int n  = r % NTILE; r /= NTILE;
    const int t  = r % K;
    const int s  = r / K;

    const int co  = n * 16 + (lane & 15);
    const int cib = s * 32 + (lane >> 4) * 8;
    __align__(16) _Float16 v8[8];
#pragma unroll
    for (int j = 0; j < 8; ++j) {
        const float v = W[((size_t)co * CIN + cib + j) * K + t];
        const _Float16 h = (_Float16)v;
        v8[j] = pl ? (_Float16)(v - (float)h) : h;
    }
    *(int4*)(wf + (size_t)i * 8) = *(const int4*)v8;
}

// ============================================================================
// MFMA fp16 implicit-GEMM conv (MODE 0: silu store; MODE 1: gate store).
// ============================================================================
template <int CIN, int COUT, int K, int DIL, int MODE>
__launch_bounds__(256, 2) __global__ void conv_mfma_k(
    const _Float16* __restrict__ in, const _Float16* __restrict__ wf,
    const float* __restrict__ bias,  const float* __restrict__ bnp,
    const _Float16* __restrict__ aux, _Float16* __restrict__ out,
    const float* __restrict__ zpage)
{
    constexpr int SL    = CIN / 32;
    constexpr int P     = SL * K;
    constexpr int PADR  = ((K - 1) / 2) * DIL;
    constexpr int LWIN  = 128 + (K - 1) * DIL;
    constexpr int NT    = COUT / 32;
    constexpr int NTILE = COUT / 16;
    constexpr int CH_IN = LWIN * 5;
    constexpr int BUFB  = LWIN * 80;
    constexpr int NBUF  = (SL > 1) ? 2 : 1;
    constexpr int ESTR  = COUT + 4;
    constexpr int EPIB  = 128 * ESTR * 2;
    constexpr int SMEMB = (NBUF * BUFB > EPIB) ? NBUF * BUFB : EPIB;

    __shared__ __align__(16) char smem[SMEMB];

    const int tid   = threadIdx.x;
    const int lane  = tid & 63;
    const int w     = tid >> 6;
    const int wl    = w >> 1;
    const int wc    = w & 1;
    const int b     = blockIdx.z;
    const int l0    = blockIdx.x * 128;
    const int lan15 = lane & 15;
    const int kgB   = (lane >> 4) * 16;

    const size_t bL = (size_t)b * L_LEN;

    auto stage_in = [&](int s, int buf) {
        const int ci0 = s * 32;
        char* dst = smem + buf * BUFB;
        for (int c = tid; c < CH_IN; c += 256) {
            const int row  = c / 5;
            const int slot = c - row * 5;
            const int gl   = l0 - PADR + row;
            const bool ok  = (slot < 4) & (gl >= 0) & (gl < L_LEN);
            const _Float16* s0 = in + ((bL + gl) * CIN + ci0 + slot * 8);
            const void* src = ok ? (const void*)s0 : (const void*)zpage;
            gload16(src, dst + (size_t)c * 16);
        }
    };

    auto loadB = [&](int p, f16x8 (&dst)[2 * NT]) {
        const _Float16* bbase = wf + (size_t)p * (NTILE * 1024);
#pragma unroll
        for (int nt = 0; nt < NT; ++nt) {
            const int ntg = wc * NT + nt;
            dst[nt * 2 + 0] = *(const f16x8*)(bbase + (ntg * 2 + 0) * 512 + lane * 8);
            dst[nt * 2 + 1] = *(const f16x8*)(bbase + (ntg * 2 + 1) * 512 + lane * 8);
        }
    };

    f32x4 acc[4][NT];
#pragma unroll
    for (int mt = 0; mt < 4; ++mt)
#pragma unroll
        for (int nt = 0; nt < NT; ++nt) acc[mt][nt] = (f32x4){0.f, 0.f, 0.f, 0.f};

    f16x8 brbuf[2][2 * NT];

    stage_in(0, 0);
    loadB(0, brbuf[0]);
    if (P > 1) loadB(1, brbuf[1]);
    asm volatile("s_waitcnt vmcnt(0)" ::: "memory");
    __builtin_amdgcn_sched_barrier(0);
    __syncthreads();

#pragma unroll
    for (int pp = 0; pp < P; ++pp) {
        const int ss = pp / K;
        const int tt = pp % K;

        if (tt == 0 && ss + 1 < SL) stage_in(ss + 1, (ss + 1) & 1);

        const char* ibase = smem + (ss & 1) * BUFB;
#pragma unroll
        for (int mt = 0; mt < 4; ++mt) {
            const int row = wl * 64 + mt * 16 + lan15 + tt * DIL;
            const f16x8 a = *(const f16x8*)(ibase + row * 80 + kgB);
#pragma unroll
            for (int nt = 0; nt < NT; ++nt) {
                acc[mt][nt] = __builtin_amdgcn_mfma_f32_16x16x32_f16(a, brbuf[pp & 1][nt * 2 + 0], acc[mt][nt], 0, 0, 0);
                acc[mt][nt] = __builtin_amdgcn_mfma_f32_16x16x32_f16(a, brbuf[pp & 1][nt * 2 + 1], acc[mt][nt], 0, 0, 0);
            }
        }

        if (pp + 2 < P) loadB(pp + 2, brbuf[pp & 1]);

        if (tt == K - 1 && ss + 1 < SL) {
            asm volatile("s_waitcnt vmcnt(0)" ::: "memory");
            __builtin_amdgcn_sched_barrier(0);
            __syncthreads();
        }
    }

    // ---- epilogue: z -> LDS -> coalesced sweep ----
    __syncthreads();
    _Float16* zl = (_Float16*)smem;
#pragma unroll
    for (int nt = 0; nt < NT; ++nt) {
        const int co = (wc * NT + nt) * 16 + lan15;
        const float g = bnp[co], be = bnp[COUT + co], mn = bnp[2 * COUT + co], vr = bnp[3 * COUT + co];
        const float sc = g * rsqrtf(vr + 1e-5f);
        const float sh = fmaf(bias[co] - mn, sc, be);
#pragma unroll
        for (int mt = 0; mt < 4; ++mt) {
#pragma unroll
            for (int r = 0; r < 4; ++r) {
                const int l_loc = wl * 64 + mt * 16 + (lane >> 4) * 4 + r;
                zl[l_loc * ESTR + co] = (_Float16)fmaf(acc[mt][nt][r], sc, sh);
            }
        }
    }
    __syncthreads();

    constexpr int CO8 = COUT / 8;
    constexpr int LG  = (CO8 == 16) ? 4 : (CO8 == 8) ? 3 : 2;
    constexpr int RPI = 64 / CO8;
    const int co = (lane & (CO8 - 1)) * 8;

#pragma unroll
    for (int s2 = 0; s2 < CO8 / 2; ++s2) {
        const int l = w * 32 + s2 * RPI + (lane >> LG);
        _Float16 z8[8];
        *(int4*)z8 = *(const int4*)&zl[l * ESTR + co];
        const size_t gidx = (bL + l0 + l) * COUT + co;
        __align__(16) _Float16 o8[8];
        if constexpr (MODE == 0) {
#pragma unroll
            for (int j = 0; j < 8; ++j) o8[j] = (_Float16)silu_f((float)z8[j]);
        } else {
            _Float16 g8[8];
            *(int4*)g8 = *(const int4*)(aux + gidx);
#pragma unroll
            for (int j = 0; j < 8; ++j) o8[j] = (_Float16)((float)g8[j] * sigm_f((float)z8[j]));
        }
        *(int4*)(out + gidx) = *(const int4*)o8;
    }
}

// ============================================================================
// FUSED residual block: r1 = silu(bn1(conv(d2))) kept in LDS (144-row halo
// tile, 4x 32-ch slice planes, 80B rows); r2 = bn2(conv(r1)); pooled
// silu(r2 + d2) -> one atomic per channel per block.
// ============================================================================
__global__ __launch_bounds__(256) void fused_res_k(
    const _Float16* __restrict__ in,      // d2 [b][l][128]
    const _Float16* __restrict__ wf1, const _Float16* __restrict__ wf2,
    const float* __restrict__ b1v, const float* __restrict__ bn1v,
    const float* __restrict__ b2v, const float* __restrict__ bn2v,
    float* __restrict__ gsum, const float* __restrict__ zpage)
{
    constexpr int NT = 4, NTILE = 8, SL = 4, K = 3, P = 12;
    constexpr int LWIN1 = 146;                 // input rows for 144 r1 rows
    constexpr int CH_IN = LWIN1 * 5;
    constexpr int BUFB  = LWIN1 * 80;          // 11680
    constexpr int R1PL  = 144 * 80;            // 11520 per 32-ch slice
    constexpr int R1OFF = 2 * BUFB;            // 23360
    constexpr int ESTR  = 132;

    __shared__ __align__(16) char smem[R1OFF + 4 * R1PL];   // 69440 B
    __shared__ float pf[4][128];

    const int tid   = threadIdx.x;
    const int lane  = tid & 63;
    const int w     = tid >> 6;
    const int wl    = w >> 1;
    const int wc    = w & 1;
    const int b     = blockIdx.z;
    const int l0    = blockIdx.x * 128;
    const int lan15 = lane & 15;
    const int kgB   = (lane >> 4) * 16;

    const size_t bL = (size_t)b * L_LEN;

    auto stage_in = [&](int s, int buf) {
        const int ci0 = s * 32;
        char* dst = smem + buf * BUFB;
        for (int c = tid; c < CH_IN; c += 256) {
            const int row  = c / 5;
            const int slot = c - row * 5;
            const int gl   = l0 - 9 + row;
            const bool ok  = (slot < 4) & (gl >= 0) & (gl < L_LEN);
            const _Float16* s0 = in + ((bL + gl) * 128 + ci0 + slot * 8);
            const void* src = ok ? (const void*)s0 : (const void*)zpage;
            gload16(src, dst + (size_t)c * 16);
        }
    };

    auto loadB = [&](const _Float16* wf, int p, f16x8 (&dst)[2 * NT]) {
        const _Float16* bbase = wf + (size_t)p * (NTILE * 1024);
#pragma unroll
        for (int nt = 0; nt < NT; ++nt) {
            const int ntg = wc * NT + nt;
            dst[nt * 2 + 0] = *(const f16x8*)(bbase + (ntg * 2 + 0) * 512 + lane * 8);
            dst[nt * 2 + 1] = *(const f16x8*)(bbase + (ntg * 2 + 1) * 512 + lane * 8);
        }
    };

    // ================= GEMM1: r1 over 144 rows [l0-8, l0+136) =================
    const int NMT   = wl ? 4 : 5;      // wl0: rows 0..79 (5 tiles), wl1: 80..143 (4)
    const int mbase = wl * 80;

    f32x4 acc1[5][NT];
#pragma unroll
    for (int mt = 0; mt < 5; ++mt)
#pragma unroll
        for (int nt = 0; nt < NT; ++nt) acc1[mt][nt] = (f32x4){0.f, 0.f, 0.f, 0.f};

    f16x8 brbuf[2][2 * NT];

    stage_in(0, 0);
    loadB(wf1, 0, brbuf[0]);
    loadB(wf1, 1, brbuf[1]);
    asm volatile("s_waitcnt vmcnt(0)" ::: "memory");
    __builtin_amdgcn_sched_barrier(0);
    __syncthreads();

#pragma unroll
    for (int pp = 0; pp < P; ++pp) {
        const int ss = pp / K;
        const int tt = pp % K;

        if (tt == 0 && ss + 1 < SL) stage_in(ss + 1, (ss + 1) & 1);

        const char* ibase = smem + (ss & 1) * BUFB;
#pragma unroll
        for (int mt = 0; mt < 5; ++mt) {
            if (mt < NMT) {
                const int row = mbase + mt * 16 + lan15 + tt;   // window row
                const f16x8 a = *(const f16x8*)(ibase + row * 80 + kgB);
#pragma unroll
                for (int nt = 0; nt < NT; ++nt) {
                    acc1[mt][nt] = __builtin_amdgcn_mfma_f32_16x16x32_f16(a, brbuf[pp & 1][nt * 2 + 0], acc1[mt][nt], 0, 0, 0);
                    acc1[mt][nt] = __builtin_amdgcn_mfma_f32_16x16x32_f16(a, brbuf[pp & 1][nt * 2 + 1], acc1[mt][nt], 0, 0, 0);
                }
            }
        }

        if (pp + 2 < P) loadB(wf1, pp + 2, brbuf[pp & 1]);

        if (tt == K - 1 && ss + 1 < SL) {
            asm volatile("s_waitcnt vmcnt(0)" ::: "memory");
            __builtin_amdgcn_sched_barrier(0);
            __syncthreads();
        }
    }

    // ---- scatter r1 = silu(bn1(z)) into LDS slice planes (zero OOB rows) ----
    _Float16* r1b = (_Float16*)(smem + R1OFF);
#pragma unroll
    for (int nt = 0; nt < NT; ++nt) {
        const int co = (wc * NT + nt) * 16 + lan15;
        const float g = bn1v[co], be = bn1v[128 + co], mn = bn1v[256 + co], vr = bn1v[384 + co];
        const float sc = g * rsqrtf(vr + 1e-5f);
        const float sh = fmaf(b1v[co] - mn, sc, be);
        _Float16* pl = r1b + (co >> 5) * (R1PL / 2) + (co & 31);
#pragma unroll
        for (int mt = 0; mt < 5; ++mt) {
            if (mt < NMT) {
#pragma unroll
                for (int r = 0; r < 4; ++r) {
                    const int tr = mbase + mt * 16 + (lane >> 4) * 4 + r;
                    const int gl = l0 - 8 + tr;
                    float v = silu_f(fmaf(acc1[mt][nt][r], sc, sh));
                    if (gl < 0 || gl >= L_LEN) v = 0.f;
                    pl[tr * 40] = (_Float16)v;
                }
            }
        }
    }
    __syncthreads();

    // ================= GEMM2: r2 over rows [l0, l0+128), A from LDS =========
    f32x4 acc2[4][NT];
#pragma unroll
    for (int mt = 0; mt < 4; ++mt)
#pragma unroll
        for (int nt = 0; nt < NT; ++nt) acc2[mt][nt] = (f32x4){0.f, 0.f, 0.f, 0.f};

    loadB(wf2, 0, brbuf[0]);
    loadB(wf2, 1, brbuf[1]);

#pragma unroll
    for (int pp = 0; pp < P; ++pp) {
        const int ss = pp / K;
        const int tt = pp % K;
        const char* ibase = smem + R1OFF + ss * R1PL;
#pragma unroll
        for (int mt = 0; mt < 4; ++mt) {
            const int tr = wl * 64 + mt * 16 + lan15 + 7 + tt;   // +8 - pad1 + tt
            const f16x8 a = *(const f16x8*)(ibase + tr * 80 + kgB);
#pragma unroll
            for (int nt = 0; nt < NT; ++nt) {
                acc2[mt][nt] = __builtin_amdgcn_mfma_f32_16x16x32_f16(a, brbuf[pp & 1][nt * 2 + 0], acc2[mt][nt], 0, 0, 0);
                acc2[mt][nt] = __builtin_amdgcn_mfma_f32_16x16x32_f16(a, brbuf[pp & 1][nt * 2 + 1], acc2[mt][nt], 0, 0, 0);
            }
        }
        if (pp + 2 < P) loadB(wf2, pp + 2, brbuf[pp & 1]);
    }

    // ---- epilogue: z2 -> LDS (r1 region, now dead) -> pooled sweep ----
    __syncthreads();
    _Float16* zl = (_Float16*)(smem + R1OFF);
#pragma unroll
    for (int nt = 0; nt < NT; ++nt) {
        const int co = (wc * NT + nt) * 16 + lan15;
        const float g = bn2v[co], be = bn2v[128 + co], mn = bn2v[256 + co], vr = bn2v[384 + co];
        const float sc = g * rsqrtf(vr + 1e-5f);
        const float sh = fmaf(b2v[co] - mn, sc, be);
#pragma unroll
        for (int mt = 0; mt < 4; ++mt) {
#pragma unroll
            for (int r = 0; r < 4; ++r) {
                const int l_loc = wl * 64 + mt * 16 + (lane >> 4) * 4 + r;
                zl[l_loc * ESTR + co] = (_Float16)fmaf(acc2[mt][nt][r], sc, sh);
            }
        }
    }
    __syncthreads();

    const int co = (lane & 15) * 8;
    float ps[8];
#pragma unroll
    for (int j = 0; j < 8; ++j) ps[j] = 0.f;

#pragma unroll
    for (int s2 = 0; s2 < 8; ++s2) {
        const int l = w * 32 + s2 * 4 + (lane >> 4);
        _Float16 z8[8];
        *(int4*)z8 = *(const int4*)&zl[l * ESTR + co];
        _Float16 a8[8];
        *(int4*)a8 = *(const int4*)(in + (bL + l0 + l) * 128 + co);
#pragma unroll
        for (int j = 0; j < 8; ++j) ps[j] += silu_f((float)z8[j] + (float)a8[j]);
    }

#pragma unroll
    for (int j = 0; j < 8; ++j) {
        ps[j] += __shfl_xor(ps[j], 16, 64);
        ps[j] += __shfl_xor(ps[j], 32, 64);
    }
    if ((lane >> 4) == 0) {
#pragma unroll
        for (int j = 0; j < 8; ++j) pf[w][co + j] = ps[j];
    }
    __syncthreads();
    if (tid < 128) {
        const float s = pf[0][tid] + pf[1][tid] + pf[2][tid] + pf[3][tid];
        atomicAdd(&gsum[b * 128 + tid], s);
    }
}

// ============================================================================
// 4-qubit statevector circuit, one thread per batch row
// ============================================================================
template <int BW> DEV void g_ry(float (&re)[16], float (&im)[16], float t) {
    float s, c; sincosf(0.5f * t, &s, &c);
#pragma unroll
    for (int i = 0; i < 16; ++i)
        if (!(i & BW)) {
            const int j = i | BW;
            float r0 = re[i], q0 = im[i], r1 = re[j], q1 = im[j];
            re[i] = c * r0 - s * r1; im[i] = c * q0 - s * q1;
            re[j] = s * r0 + c * r1; im[j] = s * q0 + c * q1;
        }
}
template <int BW> DEV void g_rz(float (&re)[16], float (&im)[16], float t) {
    float s, c; sincosf(0.5f * t, &s, &c);
#pragma unroll
    for (int i = 0; i < 16; ++i) {
        float r = re[i], q = im[i];
        if (i & BW) { re[i] = r * c - q * s; im[i] = q * c + r * s; }
        else        { re[i] = r * c + q * s; im[i] = q * c - r * s; }
    }
}
template <int BC, int BT> DEV void g_cnot(float (&re)[16], float (&im)[16]) {
#pragma unroll
    for (int i = 0; i < 16; ++i)
        if ((i & BC) && !(i & BT)) {
            const int j = i | BT;
            float r = re[i]; re[i] = re[j]; re[j] = r;
            float q = im[i]; im[i] = im[j]; im[j] = q;
        }
}

__global__ void quantum_k(const float* __restrict__ gsum, const float* __restrict__ Wfm,
                          const float* __restrict__ bfm, const float* __restrict__ qw,
                          float* __restrict__ q, int B)
{
    const int b = blockIdx.x * blockDim.x + threadIdx.x;
    if (b >= B) return;

    float qin[4];
#pragma unroll
    for (int j = 0; j < 4; ++j) qin[j] = bfm[j];
    const float inv = 1.f / (float)L_LEN;
    for (int c = 0; c < 128; ++c) {
        const float gv = gsum[b * 128 + c] * inv;
#pragma unroll
        for (int j = 0; j < 4; ++j) qin[j] = fmaf(gv, Wfm[j * 128 + c], qin[j]);
    }

    float re[16], im[16];
#pragma unroll
    for (int i = 0; i < 16; ++i) { re[i] = 0.f; im[i] = 0.f; }
    re[0] = 1.f;

    g_ry<8>(re, im, qin[0]); g_ry<4>(re, im, qin[1]); g_ry<2>(re, im, qin[2]); g_ry<1>(re, im, qin[3]);
    g_rz<8>(re, im, qw[0]);  g_ry<8>(re, im, qw[1]);
    g_rz<4>(re, im, qw[2]);  g_ry<4>(re, im, qw[3]);
    g_rz<2>(re, im, qw[4]);  g_ry<2>(re, im, qw[5]);
    g_rz<1>(re, im, qw[6]);  g_ry<1>(re, im, qw[7]);
    g_cnot<8, 4>(re, im); g_cnot<4, 2>(re, im); g_cnot<2, 1>(re, im);
    g_rz<8>(re, im, qw[8]);  g_ry<8>(re, im, qw[9]);
    g_rz<4>(re, im, qw[10]); g_ry<4>(re, im, qw[11]);
    g_rz<2>(re, im, qw[12]); g_ry<2>(re, im, qw[13]);
    g_rz<1>(re, im, qw[14]); g_ry<1>(re, im, qw[15]);

    float pr[16];
#pragma unroll
    for (int i = 0; i < 16; ++i) pr[i] = re[i] * re[i] + im[i] * im[i];
#pragma unroll
    for (int w = 0; w < 4; ++w) {
        const int bw = 8 >> w;
        float e = 0.f;
#pragma unroll
        for (int i = 0; i < 16; ++i) e += (i & bw) ? -pr[i] : pr[i];
        q[b * 4 + w] = e;
    }
}

// ============================================================================
// FC head: 4 -> 64 -> 32 -> 1
// ============================================================================
__global__ void head_k(const float* __restrict__ q,
                       const float* __restrict__ Wf1, const float* __restrict__ bf1, const float* __restrict__ bnf1,
                       const float* __restrict__ Wf2, const float* __restrict__ bf2, const float* __restrict__ bnf2,
                       const float* __restrict__ Wf3, const float* __restrict__ bf3,
                       float* __restrict__ out)
{
    const int b = blockIdx.x, t = threadIdx.x;
    __shared__ float qs[4], x1[64], x2[32];
    if (t < 4) qs[t] = q[b * 4 + t];
    __syncthreads();
    {
        float a = bf1[t];
#pragma unroll
        for (int k = 0; k < 4; ++k) a = fmaf(qs[k], Wf1[t * 4 + k], a);
        const float sc = bnf1[t] / sqrtf(bnf1[192 + t] + 1e-5f);
        const float z  = (a - bnf1[128 + t]) * sc + bnf1[64 + t];
        x1[t] = silu_f(z);
    }
    __syncthreads();
    if (t < 32) {
        float a = bf2[t];
        for (int k = 0; k < 64; ++k) a = fmaf(x1[k], Wf2[t * 64 + k], a);
        const float sc = bnf2[t] / sqrtf(bnf2[96 + t] + 1e-5f);
        const float z  = (a - bnf2[64 + t]) * sc + bnf2[32 + t];
        x2[t] = silu_f(z);
    }
    __syncthreads();
    if (t == 0) {
        float a = bf3[0];
        for (int k = 0; k < 32; ++k) a = fmaf(x2[k], Wf3[k], a);
        out[b] = a;
    }
}

// ============================================================================
extern "C" void kernel_launch(void* const* d_in, const int* in_sizes, int n_in,
                              void* d_out, int out_size, void* d_ws, size_t ws_size,
                              hipStream_t stream)
{
    (void)n_in; (void)out_size;
    const float* x    = (const float*)d_in[0];
    const float* W1   = (const float*)d_in[1];
    const float* b1   = (const float*)d_in[2];
    const float* bn1  = (const float*)d_in[3];
    const float* Wa1  = (const float*)d_in[4];
    const float* ba1  = (const float*)d_in[5];
    const float* bna1 = (const float*)d_in[6];
    const float* Wa2  = (const float*)d_in[7];
    const float* ba2  = (const float*)d_in[8];
    const float* bna2 = (const float*)d_in[9];
    const float* Wd1  = (const float*)d_in[10];
    const float* bdd1 = (const float*)d_in[11];
    const float* bnd1 = (const float*)d_in[12];
    const float* Wd2  = (const float*)d_in[13];
    const float* bdd2 = (const float*)d_in[14];
    const float* bnd2 = (const float*)d_in[15];
    const float* Wr1  = (const float*)d_in[16];
    const float* br1  = (const float*)d_in[17];
    const float* bnr1 = (const float*)d_in[18];
    const float* Wr2  = (const float*)d_in[19];
    const float* br2  = (const float*)d_in[20];
    const float* bnr2 = (const float*)d_in[21];
    const float* Wfm  = (const float*)d_in[22];
    const float* bfm  = (const float*)d_in[23];
    const float* qw   = (const float*)d_in[24];
    const float* Wf1  = (const float*)d_in[25];
    const float* bf1  = (const float*)d_in[26];
    const float* bnf1 = (const float*)d_in[27];
    const float* Wf2  = (const float*)d_in[28];
    const float* bf2  = (const float*)d_in[29];
    const float* bnf2 = (const float*)d_in[30];
    const float* Wf3  = (const float*)d_in[31];
    const float* bf3  = (const float*)d_in[32];

    const int B = in_sizes[0] / L_LEN;  // 128

    char* base = (char*)d_ws;
    size_t off = 0;
    auto alloc = [&](size_t bytes) -> char* {
        off = (off + 255) & ~(size_t)255;
        char* p = base + off;
        off += bytes;
        return p;
    };

    float* gbuf  = (float*)alloc((size_t)B * 128 * 4);
    float* qbuf  = (float*)alloc((size_t)B * 4 * 4);
    float* zpage = (float*)alloc(256);

    auto wfrag = [&](int cin, int cout, int k) -> _Float16* {
        return (_Float16*)alloc((size_t)k * cout * cin * 2 * 2);
    };
    _Float16* wa1f = wfrag(64, 32, 7);
    _Float16* wa2f = wfrag(32, 64, 7);
    _Float16* wd1f = wfrag(64, 128, 3);
    _Float16* wd2f = wfrag(128, 128, 3);
    _Float16* wr1f = wfrag(128, 128, 3);
    _Float16* wr2f = wfrag(128, 128, 3);

    const size_t fixed = (off + 255) & ~(size_t)255;
    const size_t PS = (size_t)2 * L_LEN * (64 + 32 + 128 + 128);  // fp16 planes
    size_t avail = (ws_size > fixed + 4096) ? ws_size - fixed - 4096 : 0;
    int chunk = B;
    while (chunk > 1 && (size_t)chunk * PS > avail) chunk >>= 1;

    auto aplane = [&](int C, int c) -> _Float16* {
        return (_Float16*)alloc((size_t)c * L_LEN * C * 2);
    };
    _Float16* h0 = aplane(64,  chunk);
    _Float16* a1 = aplane(32,  chunk);
    _Float16* d1 = aplane(128, chunk);
    _Float16* d2 = aplane(128, chunk);

    auto pg = [](int tot) { return dim3((tot + 255) / 256); };
    prep_w_k<64, 32, 7>  <<<pg(2*7*2*2*64),  dim3(256), 0, stream>>>(Wa1, wa1f);
    prep_w_k<32, 64, 7>  <<<pg(1*7*4*2*64),  dim3(256), 0, stream>>>(Wa2, wa2f);
    prep_w_k<64, 128, 3> <<<pg(2*3*8*2*64),  dim3(256), 0, stream>>>(Wd1, wd1f);
    prep_w_k<128, 128, 3><<<pg(4*3*8*2*64),  dim3(256), 0, stream>>>(Wd2, wd2f);
    prep_w_k<128, 128, 3><<<pg(4*3*8*2*64),  dim3(256), 0, stream>>>(Wr1, wr1f);
    prep_w_k<128, 128, 3><<<pg(4*3*8*2*64),  dim3(256), 0, stream>>>(Wr2, wr2f);

    hipMemsetAsync(gbuf, 0, (size_t)B * 128 * sizeof(float), stream);
    hipMemsetAsync(zpage, 0, 256, stream);

    const dim3 blk(256);
    for (int sft = 0; sft < B; sft += chunk) {
        const int c = (chunk < B - sft) ? chunk : (B - sft);
        const dim3 cg(L_LEN / 128, 1, c);
        conv1_k<<<dim3(64, c), blk, 0, stream>>>(x + (size_t)sft * L_LEN, W1, b1, bn1, h0);
        conv_mfma_k<64, 32, 7, 1, 0><<<cg, blk, 0, stream>>>(h0, wa1f, ba1, bna1, nullptr, a1, zpage);
        conv_mfma_k<32, 64, 7, 1, 1><<<cg, blk, 0, stream>>>(a1, wa2f, ba2, bna2, h0, h0, zpage);
        conv_mfma_k<64, 128, 3, 2, 0><<<cg, blk, 0, stream>>>(h0, wd1f, bdd1, bnd1, nullptr, d1, zpage);
        conv_mfma_k<128, 128, 3, 4, 0><<<cg, blk, 0, stream>>>(d1, wd2f, bdd2, bnd2, nullptr, d2, zpage);
        fused_res_k<<<cg, blk, 0, stream>>>(d2, wr1f, wr2f, br1, bnr1, br2, bnr2,
                                            gbuf + (size_t)sft * 128, zpage);
    }

    quantum_k<<<dim3((B + 127) / 128), dim3(128), 0, stream>>>(gbuf, Wfm, bfm, qw, qbuf, B);
    head_k<<<dim3(B), dim3(64), 0, stream>>>(qbuf, Wf1, bf1, bnf1, Wf2, bf2, bnf2, Wf3, bf3, (float*)d_out);
}

// Round 10
// 629.068 us; speedup vs baseline: 1.3157x; 1.3157x over previous
//
#include <hip/hip_runtime.h>
#include <math.h>

#define L_LEN 4096
#define DEV __device__ __forceinline__

typedef __attribute__((ext_vector_type(8))) _Float16 f16x8;
typedef __attribute__((ext_vector_type(4))) float   f32x4;

DEV float fexp_f(float x) { return exp2f(1.44269504f * x); }          // e^x
DEV float silu_f(float x) { return x * __builtin_amdgcn_rcpf(1.f + fexp_f(-x)); }
DEV float sigm_f(float x) { return __builtin_amdgcn_rcpf(1.f + fexp_f(-x)); }

DEV void gload16(const void* g, void* l) {
    __builtin_amdgcn_global_load_lds(
        (const __attribute__((address_space(1))) void*)g,
        (__attribute__((address_space(3))) void*)l, 16, 0, 0);
}

// ============================================================================
// conv1: CIN=1, K=5, pad=2 (fp32 direct; writes fp16 channels-last)
// ============================================================================
__global__ __launch_bounds__(256) void conv1_k(
    const float* __restrict__ x, const float* __restrict__ W,
    const float* __restrict__ bias, const float* __restrict__ bnp,
    _Float16* __restrict__ out)
{
    __shared__ float sw[64 * 5];
    __shared__ float ssc[64], ssh[64];
    const int tid = threadIdx.x;
    if (tid < 64) {
        float g = bnp[tid], be = bnp[64 + tid], mn = bnp[128 + tid], vr = bnp[192 + tid];
        float sc = g * rsqrtf(vr + 1e-5f);
        ssc[tid] = sc;
        ssh[tid] = fmaf(bias[tid] - mn, sc, be);
    }
    for (int i = tid; i < 320; i += 256) sw[i] = W[i];
    __syncthreads();

    const int b = blockIdx.y;
    const int l = blockIdx.x * 64 + (tid >> 2);
    const int cq = (tid & 3) * 16;

    float win[5];
#pragma unroll
    for (int k = 0; k < 5; ++k) {
        int ix = l + k - 2;
        win[k] = (ix >= 0 && ix < L_LEN) ? x[(size_t)b * L_LEN + ix] : 0.f;
    }
    __align__(16) _Float16 vv[16];
#pragma unroll
    for (int j = 0; j < 16; ++j) {
        const int co = cq + j;
        float z = 0.f;
#pragma unroll
        for (int k = 0; k < 5; ++k) z = fmaf(sw[co * 5 + k], win[k], z);
        z = fmaf(z, ssc[co], ssh[co]);
        vv[j] = (_Float16)silu_f(z);
    }
    const size_t o = ((size_t)b * L_LEN + l) * 64 + cq;
    *(int4*)(out + o)     = *(const int4*)(vv);
    *(int4*)(out + o + 8) = *(const int4*)(vv + 8);
}

// ============================================================================
// weight prep -> fragment-order fp16 split: [s][t][n][pl][lane][8]
// ============================================================================
template <int CIN, int COUT, int K>
__global__ void prep_w_k(const float* __restrict__ W, _Float16* __restrict__ wf)
{
    constexpr int NTILE = COUT / 16;
    const int i = blockIdx.x * 256 + threadIdx.x;
    const int total = (CIN / 32) * K * NTILE * 2 * 64;
    if (i >= total) return;
    const int lane = i & 63;
    int r = i >> 6;
    const int pl = r & 1;  r >>= 1;
    const int n  = r % NTILE; r /= NTILE;
    const int t  = r % K;
    const int s  = r / K;

    const int co  = n * 16 + (lane & 15);
    const int cib = s * 32 + (lane >> 4) * 8;
    __align__(16) _Float16 v8[8];
#pragma unroll
    for (int j = 0; j < 8; ++j) {
        const float v = W[((size_t)co * CIN + cib + j) * K + t];
        const _Float16 h = (_Float16)v;
        v8[j] = pl ? (_Float16)(v - (float)h) : h;
    }
    *(int4*)(wf + (size_t)i * 8) = *(const int4*)v8;
}

// ============================================================================
// MFMA fp16 implicit-GEMM conv — full-CIN single stage, barrier-free phases.
// Block: 256 thr = 4 waves (2 wl x 2 wc); tile = 128 l x COUT.
// A: whole input window staged once into LDS, row stride CIN*2+16 B (bank-
// spread pad). B: fragment-order weights, 2-phase-ahead register prefetch.
// MFMA operands SWAPPED: D[co][l] -> lane holds 4 consecutive co -> epilogue
// scatter is ds_write_b64 (conflict-free). Sweep: coalesced stores/pool.
// MODE 0: silu; MODE 1: aux*sigmoid(z) (in-place safe); MODE 3: pooled silu.
// ============================================================================
template <int CIN, int COUT, int K, int DIL, int MODE>
__launch_bounds__(256, 2) __global__ void conv_mfma_k(
    const _Float16* __restrict__ in, const _Float16* __restrict__ wf,
    const float* __restrict__ bias,  const float* __restrict__ bnp,
    const _Float16* __restrict__ aux, _Float16* __restrict__ out,
    float* __restrict__ gsum, const float* __restrict__ zpage)
{
    constexpr int SL    = CIN / 32;
    constexpr int P     = SL * K;
    constexpr int PADR  = ((K - 1) / 2) * DIL;
    constexpr int LWIN  = 128 + (K - 1) * DIL;
    constexpr int NT    = COUT / 32;
    constexpr int NTILE = COUT / 16;
    constexpr int SLOTS = CIN / 8 + 1;          // 16B chunks per row (+1 pad)
    constexpr int RSTR  = SLOTS * 16;           // row stride bytes
    constexpr int CH_IN = LWIN * SLOTS;
    constexpr int STGB  = LWIN * RSTR;
    constexpr int ESTR  = COUT + 4;             // epilogue row stride (halves)
    constexpr int EPIB  = 128 * ESTR * 2;
    constexpr int SMEMB = (STGB > EPIB) ? STGB : EPIB;

    __shared__ __align__(16) char smem[SMEMB];
    __shared__ float pf[(MODE == 3) ? 4 : 1][COUT];

    const int tid   = threadIdx.x;
    const int lane  = tid & 63;
    const int w     = tid >> 6;
    const int wl    = w >> 1;
    const int wc    = w & 1;
    const int b     = blockIdx.z;
    const int l0    = blockIdx.x * 128;
    const int lan15 = lane & 15;
    const int kgB   = (lane >> 4) * 16;

    const size_t bL = (size_t)b * L_LEN;

    auto loadB = [&](int p, f16x8 (&dst)[2 * NT]) {
        const _Float16* bbase = wf + (size_t)p * (NTILE * 1024);
#pragma unroll
        for (int nt = 0; nt < NT; ++nt) {
            const int ntg = wc * NT + nt;
            dst[nt * 2 + 0] = *(const f16x8*)(bbase + (ntg * 2 + 0) * 512 + lane * 8);
            dst[nt * 2 + 1] = *(const f16x8*)(bbase + (ntg * 2 + 1) * 512 + lane * 8);
        }
    };

    f32x4 acc[4][NT];
#pragma unroll
    for (int mt = 0; mt < 4; ++mt)
#pragma unroll
        for (int nt = 0; nt < NT; ++nt) acc[mt][nt] = (f32x4){0.f, 0.f, 0.f, 0.f};

    f16x8 brbuf[2][2 * NT];

    // ---- stage the ENTIRE input window once (lane-linear dst) ----
    for (int c = tid; c < CH_IN; c += 256) {
        const int row  = c / SLOTS;
        const int slot = c - row * SLOTS;
        const int gl   = l0 - PADR + row;
        const bool ok  = (slot < SLOTS - 1) & (gl >= 0) & (gl < L_LEN);
        const _Float16* s0 = in + ((bL + gl) * CIN + slot * 8);
        const void* src = ok ? (const void*)s0 : (const void*)zpage;
        gload16(src, smem + (size_t)c * 16);
    }
    loadB(0, brbuf[0]);
    if (P > 1) loadB(1, brbuf[1]);
    asm volatile("s_waitcnt vmcnt(0)" ::: "memory");
    __builtin_amdgcn_sched_barrier(0);
    __syncthreads();

    // ---- barrier-free static phase loop ----
#pragma unroll
    for (int pp = 0; pp < P; ++pp) {
        const int ss = pp / K;
        const int tt = pp % K;
#pragma unroll
        for (int mt = 0; mt < 4; ++mt) {
            const int row = wl * 64 + mt * 16 + lan15 + tt * DIL;
            const f16x8 a = *(const f16x8*)(smem + row * RSTR + ss * 64 + kgB);
#pragma unroll
            for (int nt = 0; nt < NT; ++nt) {
                // swapped operands: D rows = co, cols = l
                acc[mt][nt] = __builtin_amdgcn_mfma_f32_16x16x32_f16(brbuf[pp & 1][nt * 2 + 0], a, acc[mt][nt], 0, 0, 0);
                acc[mt][nt] = __builtin_amdgcn_mfma_f32_16x16x32_f16(brbuf[pp & 1][nt * 2 + 1], a, acc[mt][nt], 0, 0, 0);
            }
        }
        if (pp + 2 < P) loadB(pp + 2, brbuf[pp & 1]);   // WAR-safe: after reads
    }

    // ---- epilogue: z -> LDS (b64 scatter, 4 consecutive co/lane) ----
    __syncthreads();   // all staging reads done before smem reuse
    _Float16* zl = (_Float16*)smem;
#pragma unroll
    for (int nt = 0; nt < NT; ++nt) {
        const int co0 = (wc * NT + nt) * 16 + (lane >> 4) * 4;
        const float4 g4 = *(const float4*)&bnp[co0];
        const float4 b4 = *(const float4*)&bnp[COUT + co0];
        const float4 m4 = *(const float4*)&bnp[2 * COUT + co0];
        const float4 v4 = *(const float4*)&bnp[3 * COUT + co0];
        const float4 bi = *(const float4*)&bias[co0];
        float sc[4], sh[4];
        sc[0] = g4.x * rsqrtf(v4.x + 1e-5f); sh[0] = fmaf(bi.x - m4.x, sc[0], b4.x);
        sc[1] = g4.y * rsqrtf(v4.y + 1e-5f); sh[1] = fmaf(bi.y - m4.y, sc[1], b4.y);
        sc[2] = g4.z * rsqrtf(v4.z + 1e-5f); sh[2] = fmaf(bi.z - m4.z, sc[2], b4.z);
        sc[3] = g4.w * rsqrtf(v4.w + 1e-5f); sh[3] = fmaf(bi.w - m4.w, sc[3], b4.w);
#pragma unroll
        for (int mt = 0; mt < 4; ++mt) {
            const int l_loc = wl * 64 + mt * 16 + lan15;
            __align__(8) _Float16 h4[4];
#pragma unroll
            for (int r = 0; r < 4; ++r)
                h4[r] = (_Float16)fmaf(acc[mt][nt][r], sc[r], sh[r]);
            *(int2*)&zl[l_loc * ESTR + co0] = *(const int2*)h4;
        }
    }
    __syncthreads();

    // ---- coalesced sweep ----
    constexpr int CO8 = COUT / 8;
    constexpr int LG  = (CO8 == 16) ? 4 : (CO8 == 8) ? 3 : 2;
    constexpr int RPI = 64 / CO8;
    const int co = (lane & (CO8 - 1)) * 8;

    float ps[8];
#pragma unroll
    for (int j = 0; j < 8; ++j) ps[j] = 0.f;

#pragma unroll
    for (int s2 = 0; s2 < CO8 / 2; ++s2) {
        const int l = w * 32 + s2 * RPI + (lane >> LG);
        _Float16 z8[8];
        *(int4*)z8 = *(const int4*)&zl[l * ESTR + co];
        const size_t gidx = (bL + l0 + l) * COUT + co;
        if constexpr (MODE == 0) {
            __align__(16) _Float16 o8[8];
#pragma unroll
            for (int j = 0; j < 8; ++j) o8[j] = (_Float16)silu_f((float)z8[j]);
            *(int4*)(out + gidx) = *(const int4*)o8;
        } else if constexpr (MODE == 1) {
            _Float16 g8[8];
            *(int4*)g8 = *(const int4*)(aux + gidx);
            __align__(16) _Float16 o8[8];
#pragma unroll
            for (int j = 0; j < 8; ++j) o8[j] = (_Float16)((float)g8[j] * sigm_f((float)z8[j]));
            *(int4*)(out + gidx) = *(const int4*)o8;
        } else {
            _Float16 a8[8];
            *(int4*)a8 = *(const int4*)(aux + gidx);
#pragma unroll
            for (int j = 0; j < 8; ++j) ps[j] += silu_f((float)z8[j] + (float)a8[j]);
        }
    }

    if constexpr (MODE == 3) {
#pragma unroll
        for (int j = 0; j < 8; ++j) {
#pragma unroll
            for (int m = CO8; m < 64; m <<= 1)
                ps[j] += __shfl_xor(ps[j], m, 64);
        }
        if (lane < CO8) {
#pragma unroll
            for (int j = 0; j < 8; ++j) pf[w][co + j] = ps[j];
        }
        __syncthreads();
        if (tid < COUT) {
            const float s = pf[0][tid] + pf[1][tid] + pf[2][tid] + pf[3][tid];
            atomicAdd(&gsum[b * COUT + tid], s);
        }
    }
}

// ============================================================================
// 4-qubit statevector circuit, one thread per batch row
// ============================================================================
template <int BW> DEV void g_ry(float (&re)[16], float (&im)[16], float t) {
    float s, c; sincosf(0.5f * t, &s, &c);
#pragma unroll
    for (int i = 0; i < 16; ++i)
        if (!(i & BW)) {
            const int j = i | BW;
            float r0 = re[i], q0 = im[i], r1 = re[j], q1 = im[j];
            re[i] = c * r0 - s * r1; im[i] = c * q0 - s * q1;
            re[j] = s * r0 + c * r1; im[j] = s * q0 + c * q1;
        }
}
template <int BW> DEV void g_rz(float (&re)[16], float (&im)[16], float t) {
    float s, c; sincosf(0.5f * t, &s, &c);
#pragma unroll
    for (int i = 0; i < 16; ++i) {
        float r = re[i], q = im[i];
        if (i & BW) { re[i] = r * c - q * s; im[i] = q * c + r * s; }
        else        { re[i] = r * c + q * s; im[i] = q * c - r * s; }
    }
}
template <int BC, int BT> DEV void g_cnot(float (&re)[16], float (&im)[16]) {
#pragma unroll
    for (int i = 0; i < 16; ++i)
        if ((i & BC) && !(i & BT)) {
            const int j = i | BT;
            float r = re[i]; re[i] = re[j]; re[j] = r;
            float q = im[i]; im[i] = im[j]; im[j] = q;
        }
}

__global__ void quantum_k(const float* __restrict__ gsum, const float* __restrict__ Wfm,
                          const float* __restrict__ bfm, const float* __restrict__ qw,
                          float* __restrict__ q, int B)
{
    const int b = blockIdx.x * blockDim.x + threadIdx.x;
    if (b >= B) return;

    float qin[4];
#pragma unroll
    for (int j = 0; j < 4; ++j) qin[j] = bfm[j];
    const float inv = 1.f / (float)L_LEN;
    for (int c = 0; c < 128; ++c) {
        const float gv = gsum[b * 128 + c] * inv;
#pragma unroll
        for (int j = 0; j < 4; ++j) qin[j] = fmaf(gv, Wfm[j * 128 + c], qin[j]);
    }

    float re[16], im[16];
#pragma unroll
    for (int i = 0; i < 16; ++i) { re[i] = 0.f; im[i] = 0.f; }
    re[0] = 1.f;

    g_ry<8>(re, im, qin[0]); g_ry<4>(re, im, qin[1]); g_ry<2>(re, im, qin[2]); g_ry<1>(re, im, qin[3]);
    g_rz<8>(re, im, qw[0]);  g_ry<8>(re, im, qw[1]);
    g_rz<4>(re, im, qw[2]);  g_ry<4>(re, im, qw[3]);
    g_rz<2>(re, im, qw[4]);  g_ry<2>(re, im, qw[5]);
    g_rz<1>(re, im, qw[6]);  g_ry<1>(re, im, qw[7]);
    g_cnot<8, 4>(re, im); g_cnot<4, 2>(re, im); g_cnot<2, 1>(re, im);
    g_rz<8>(re, im, qw[8]);  g_ry<8>(re, im, qw[9]);
    g_rz<4>(re, im, qw[10]); g_ry<4>(re, im, qw[11]);
    g_rz<2>(re, im, qw[12]); g_ry<2>(re, im, qw[13]);
    g_rz<1>(re, im, qw[14]); g_ry<1>(re, im, qw[15]);

    float pr[16];
#pragma unroll
    for (int i = 0; i < 16; ++i) pr[i] = re[i] * re[i] + im[i] * im[i];
#pragma unroll
    for (int w = 0; w < 4; ++w) {
        const int bw = 8 >> w;
        float e = 0.f;
#pragma unroll
        for (int i = 0; i < 16; ++i) e += (i & bw) ? -pr[i] : pr[i];
        q[b * 4 + w] = e;
    }
}

// ============================================================================
// FC head: 4 -> 64 -> 32 -> 1
// ============================================================================
__global__ void head_k(const float* __restrict__ q,
                       const float* __restrict__ Wf1, const float* __restrict__ bf1, const float* __restrict__ bnf1,
                       const float* __restrict__ Wf2, const float* __restrict__ bf2, const float* __restrict__ bnf2,
                       const float* __restrict__ Wf3, const float* __restrict__ bf3,
                       float* __restrict__ out)
{
    const int b = blockIdx.x, t = threadIdx.x;
    __shared__ float qs[4], x1[64], x2[32];
    if (t < 4) qs[t] = q[b * 4 + t];
    __syncthreads();
    {
        float a = bf1[t];
#pragma unroll
        for (int k = 0; k < 4; ++k) a = fmaf(qs[k], Wf1[t * 4 + k], a);
        const float sc = bnf1[t] / sqrtf(bnf1[192 + t] + 1e-5f);
        const float z  = (a - bnf1[128 + t]) * sc + bnf1[64 + t];
        x1[t] = silu_f(z);
    }
    __syncthreads();
    if (t < 32) {
        float a = bf2[t];
        for (int k = 0; k < 64; ++k) a = fmaf(x1[k], Wf2[t * 64 + k], a);
        const float sc = bnf2[t] / sqrtf(bnf2[96 + t] + 1e-5f);
        const float z  = (a - bnf2[64 + t]) * sc + bnf2[32 + t];
        x2[t] = silu_f(z);
    }
    __syncthreads();
    if (t == 0) {
        float a = bf3[0];
        for (int k = 0; k < 32; ++k) a = fmaf(x2[k], Wf3[k], a);
        out[b] = a;
    }
}

// ============================================================================
extern "C" void kernel_launch(void* const* d_in, const int* in_sizes, int n_in,
                              void* d_out, int out_size, void* d_ws, size_t ws_size,
                              hipStream_t stream)
{
    (void)n_in; (void)out_size;
    const float* x    = (const float*)d_in[0];
    const float* W1   = (const float*)d_in[1];
    const float* b1   = (const float*)d_in[2];
    const float* bn1  = (const float*)d_in[3];
    const float* Wa1  = (const float*)d_in[4];
    const float* ba1  = (const float*)d_in[5];
    const float* bna1 = (const float*)d_in[6];
    const float* Wa2  = (const float*)d_in[7];
    const float* ba2  = (const float*)d_in[8];
    const float* bna2 = (const float*)d_in[9];
    const float* Wd1  = (const float*)d_in[10];
    const float* bdd1 = (const float*)d_in[11];
    const float* bnd1 = (const float*)d_in[12];
    const float* Wd2  = (const float*)d_in[13];
    const float* bdd2 = (const float*)d_in[14];
    const float* bnd2 = (const float*)d_in[15];
    const float* Wr1  = (const float*)d_in[16];
    const float* br1  = (const float*)d_in[17];
    const float* bnr1 = (const float*)d_in[18];
    const float* Wr2  = (const float*)d_in[19];
    const float* br2  = (const float*)d_in[20];
    const float* bnr2 = (const float*)d_in[21];
    const float* Wfm  = (const float*)d_in[22];
    const float* bfm  = (const float*)d_in[23];
    const float* qw   = (const float*)d_in[24];
    const float* Wf1  = (const float*)d_in[25];
    const float* bf1  = (const float*)d_in[26];
    const float* bnf1 = (const float*)d_in[27];
    const float* Wf2  = (const float*)d_in[28];
    const float* bf2  = (const float*)d_in[29];
    const float* bnf2 = (const float*)d_in[30];
    const float* Wf3  = (const float*)d_in[31];
    const float* bf3  = (const float*)d_in[32];

    const int B = in_sizes[0] / L_LEN;  // 128

    char* base = (char*)d_ws;
    size_t off = 0;
    auto alloc = [&](size_t bytes) -> char* {
        off = (off + 255) & ~(size_t)255;
        char* p = base + off;
        off += bytes;
        return p;
    };

    float* gbuf  = (float*)alloc((size_t)B * 128 * 4);
    float* qbuf  = (float*)alloc((size_t)B * 4 * 4);
    float* zpage = (float*)alloc(256);

    auto wfrag = [&](int cin, int cout, int k) -> _Float16* {
        return (_Float16*)alloc((size_t)k * cout * cin * 2 * 2);
    };
    _Float16* wa1f = wfrag(64, 32, 7);
    _Float16* wa2f = wfrag(32, 64, 7);
    _Float16* wd1f = wfrag(64, 128, 3);
    _Float16* wd2f = wfrag(128, 128, 3);
    _Float16* wr1f = wfrag(128, 128, 3);
    _Float16* wr2f = wfrag(128, 128, 3);

    const size_t fixed = (off + 255) & ~(size_t)255;
    const size_t PS = (size_t)2 * L_LEN * (64 + 32 + 128 + 128);  // fp16 planes
    size_t avail = (ws_size > fixed + 4096) ? ws_size - fixed - 4096 : 0;
    int chunk = B;
    while (chunk > 1 && (size_t)chunk * PS > avail) chunk >>= 1;

    auto aplane = [&](int C, int c) -> _Float16* {
        return (_Float16*)alloc((size_t)c * L_LEN * C * 2);
    };
    _Float16* h0 = aplane(64,  chunk);
    _Float16* a1 = aplane(32,  chunk);
    _Float16* d1 = aplane(128, chunk);   // also reused for r1
    _Float16* d2 = aplane(128, chunk);
    _Float16* r1 = d1;

    auto pg = [](int tot) { return dim3((tot + 255) / 256); };
    prep_w_k<64, 32, 7>  <<<pg(2*7*2*2*64),  dim3(256), 0, stream>>>(Wa1, wa1f);
    prep_w_k<32, 64, 7>  <<<pg(1*7*4*2*64),  dim3(256), 0, stream>>>(Wa2, wa2f);
    prep_w_k<64, 128, 3> <<<pg(2*3*8*2*64),  dim3(256), 0, stream>>>(Wd1, wd1f);
    prep_w_k<128, 128, 3><<<pg(4*3*8*2*64),  dim3(256), 0, stream>>>(Wd2, wd2f);
    prep_w_k<128, 128, 3><<<pg(4*3*8*2*64),  dim3(256), 0, stream>>>(Wr1, wr1f);
    prep_w_k<128, 128, 3><<<pg(4*3*8*2*64),  dim3(256), 0, stream>>>(Wr2, wr2f);

    hipMemsetAsync(gbuf, 0, (size_t)B * 128 * sizeof(float), stream);
    hipMemsetAsync(zpage, 0, 256, stream);

    const dim3 blk(256);
    for (int sft = 0; sft < B; sft += chunk) {
        const int c = (chunk < B - sft) ? chunk : (B - sft);
        const dim3 cg(L_LEN / 128, 1, c);
        conv1_k<<<dim3(64, c), blk, 0, stream>>>(x + (size_t)sft * L_LEN, W1, b1, bn1, h0);
        conv_mfma_k<64, 32, 7, 1, 0><<<cg, blk, 0, stream>>>(h0, wa1f, ba1, bna1, nullptr, a1, nullptr, zpage);
        conv_mfma_k<32, 64, 7, 1, 1><<<cg, blk, 0, stream>>>(a1, wa2f, ba2, bna2, h0, h0, nullptr, zpage);
        conv_mfma_k<64, 128, 3, 2, 0><<<cg, blk, 0, stream>>>(h0, wd1f, bdd1, bnd1, nullptr, d1, nullptr, zpage);
        conv_mfma_k<128, 128, 3, 4, 0><<<cg, blk, 0, stream>>>(d1, wd2f, bdd2, bnd2, nullptr, d2, nullptr, zpage);
        conv_mfma_k<128, 128, 3, 1, 0><<<cg, blk, 0, stream>>>(d2, wr1f, br1, bnr1, nullptr, r1, nullptr, zpage);
        conv_mfma_k<128, 128, 3, 1, 3><<<cg, blk, 0, stream>>>(r1, wr2f, br2, bnr2, d2, nullptr, gbuf + (size_t)sft * 128, zpage);
    }

    quantum_k<<<dim3((B + 127) / 128), dim3(128), 0, stream>>>(gbuf, Wfm, bfm, qw, qbuf, B);
    head_k<<<dim3(B), dim3(64), 0, stream>>>(qbuf, Wf1, bf1, bnf1, Wf2, bf2, bnf2, Wf3, bf3, (float*)d_out);
}

// Round 11
// 467.933 us; speedup vs baseline: 1.7688x; 1.3444x over previous
//
#include <hip/hip_runtime.h>
#include <math.h>

#define L_LEN 4096
#define DEV __device__ __forceinline__

typedef __attribute__((ext_vector_type(8))) _Float16 f16x8;
typedef __attribute__((ext_vector_type(4))) float   f32x4;

DEV float fexp_f(float x) { return exp2f(1.44269504f * x); }          // e^x
DEV float silu_f(float x) { return x * __builtin_amdgcn_rcpf(1.f + fexp_f(-x)); }
DEV float sigm_f(float x) { return __builtin_amdgcn_rcpf(1.f + fexp_f(-x)); }

DEV void gload16(const void* g, void* l) {
    __builtin_amdgcn_global_load_lds(
        (const __attribute__((address_space(1))) void*)g,
        (__attribute__((address_space(3))) void*)l, 16, 0, 0);
}

// ============================================================================
// conv1: CIN=1, K=5, pad=2 (fp32 direct; writes fp16 channels-last)
// ============================================================================
__global__ __launch_bounds__(256) void conv1_k(
    const float* __restrict__ x, const float* __restrict__ W,
    const float* __restrict__ bias, const float* __restrict__ bnp,
    _Float16* __restrict__ out)
{
    __shared__ float sw[64 * 5];
    __shared__ float ssc[64], ssh[64];
    const int tid = threadIdx.x;
    if (tid < 64) {
        float g = bnp[tid], be = bnp[64 + tid], mn = bnp[128 + tid], vr = bnp[192 + tid];
        float sc = g * rsqrtf(vr + 1e-5f);
        ssc[tid] = sc;
        ssh[tid] = fmaf(bias[tid] - mn, sc, be);
    }
    for (int i = tid; i < 320; i += 256) sw[i] = W[i];
    __syncthreads();

    const int b = blockIdx.y;
    const int l = blockIdx.x * 64 + (tid >> 2);
    const int cq = (tid & 3) * 16;

    float win[5];
#pragma unroll
    for (int k = 0; k < 5; ++k) {
        int ix = l + k - 2;
        win[k] = (ix >= 0 && ix < L_LEN) ? x[(size_t)b * L_LEN + ix] : 0.f;
    }
    __align__(16) _Float16 vv[16];
#pragma unroll
    for (int j = 0; j < 16; ++j) {
        const int co = cq + j;
        float z = 0.f;
#pragma unroll
        for (int k = 0; k < 5; ++k) z = fmaf(sw[co * 5 + k], win[k], z);
        z = fmaf(z, ssc[co], ssh[co]);
        vv[j] = (_Float16)silu_f(z);
    }
    const size_t o = ((size_t)b * L_LEN + l) * 64 + cq;
    *(int4*)(out + o)     = *(const int4*)(vv);
    *(int4*)(out + o + 8) = *(const int4*)(vv + 8);
}

// ============================================================================
// weight prep -> fragment-order fp16 (single plane): [s][t][n][lane][8]
//   co = n*16 + (lane&15), ci = s*32 + (lane>>4)*8 + j
// ============================================================================
template <int CIN, int COUT, int K>
__global__ void prep_w_k(const float* __restrict__ W, _Float16* __restrict__ wf)
{
    constexpr int NTILE = COUT / 16;
    const int i = blockIdx.x * 256 + threadIdx.x;
    const int total = (CIN / 32) * K * NTILE * 64;
    if (i >= total) return;
    const int lane = i & 63;
    int r = i >> 6;
    const int n  = r % NTILE; r /= NTILE;
    const int t  = r % K;
    const int s  = r / K;

    const int co  = n * 16 + (lane & 15);
    const int cib = s * 32 + (lane >> 4) * 8;
    __align__(16) _Float16 v8[8];
#pragma unroll
    for (int j = 0; j < 8; ++j)
        v8[j] = (_Float16)W[((size_t)co * CIN + cib + j) * K + t];
    *(int4*)(wf + (size_t)i * 8) = *(const int4*)v8;
}

// ============================================================================
// MFMA fp16 implicit-GEMM conv — full-CIN single stage, barrier-free phases,
// single fp16 weight term.
// Block: 256 thr = 4 waves (2 wl x 2 wc); tile = 128 l x COUT.
// A: whole input window staged once into LDS, row stride CIN*2+16 B.
// B: fragment-order weights, 2-phase-ahead register prefetch (brbuf[2][NT]).
// MFMA operands SWAPPED: D[co][l] -> lane holds 4 consecutive co -> epilogue
// scatter is ds_write_b64 (conflict-free). Sweep: coalesced stores/pool.
// MODE 0: silu; MODE 1: aux*sigmoid(z) (in-place safe); MODE 3: pooled silu.
// ============================================================================
template <int CIN, int COUT, int K, int DIL, int MODE>
__launch_bounds__(256, 2) __global__ void conv_mfma_k(
    const _Float16* __restrict__ in, const _Float16* __restrict__ wf,
    const float* __restrict__ bias,  const float* __restrict__ bnp,
    const _Float16* __restrict__ aux, _Float16* __restrict__ out,
    float* __restrict__ gsum, const float* __restrict__ zpage)
{
    constexpr int SL    = CIN / 32;
    constexpr int P     = SL * K;
    constexpr int PADR  = ((K - 1) / 2) * DIL;
    constexpr int LWIN  = 128 + (K - 1) * DIL;
    constexpr int NT    = COUT / 32;
    constexpr int NTILE = COUT / 16;
    constexpr int SLOTS = CIN / 8 + 1;          // 16B chunks per row (+1 pad)
    constexpr int RSTR  = SLOTS * 16;           // row stride bytes
    constexpr int CH_IN = LWIN * SLOTS;
    constexpr int STGB  = LWIN * RSTR;
    constexpr int ESTR  = COUT + 4;             // epilogue row stride (halves)
    constexpr int EPIB  = 128 * ESTR * 2;
    constexpr int SMEMB = (STGB > EPIB) ? STGB : EPIB;

    __shared__ __align__(16) char smem[SMEMB];
    __shared__ float pf[(MODE == 3) ? 4 : 1][COUT];

    const int tid   = threadIdx.x;
    const int lane  = tid & 63;
    const int w     = tid >> 6;
    const int wl    = w >> 1;
    const int wc    = w & 1;
    const int b     = blockIdx.z;
    const int l0    = blockIdx.x * 128;
    const int lan15 = lane & 15;
    const int kgB   = (lane >> 4) * 16;

    const size_t bL = (size_t)b * L_LEN;

    auto loadB = [&](int p, f16x8 (&dst)[NT]) {
        const _Float16* bbase = wf + (size_t)p * (NTILE * 512);
#pragma unroll
        for (int nt = 0; nt < NT; ++nt) {
            const int ntg = wc * NT + nt;
            dst[nt] = *(const f16x8*)(bbase + ntg * 512 + lane * 8);
        }
    };

    f32x4 acc[4][NT];
#pragma unroll
    for (int mt = 0; mt < 4; ++mt)
#pragma unroll
        for (int nt = 0; nt < NT; ++nt) acc[mt][nt] = (f32x4){0.f, 0.f, 0.f, 0.f};

    f16x8 brbuf[2][NT];

    // ---- stage the ENTIRE input window once (lane-linear dst) ----
    for (int c = tid; c < CH_IN; c += 256) {
        const int row  = c / SLOTS;
        const int slot = c - row * SLOTS;
        const int gl   = l0 - PADR + row;
        const bool ok  = (slot < SLOTS - 1) & (gl >= 0) & (gl < L_LEN);
        const _Float16* s0 = in + ((bL + gl) * CIN + slot * 8);
        const void* src = ok ? (const void*)s0 : (const void*)zpage;
        gload16(src, smem + (size_t)c * 16);
    }
    loadB(0, brbuf[0]);
    if (P > 1) loadB(1, brbuf[1]);
    asm volatile("s_waitcnt vmcnt(0)" ::: "memory");
    __builtin_amdgcn_sched_barrier(0);
    __syncthreads();

    // ---- barrier-free static phase loop ----
#pragma unroll
    for (int pp = 0; pp < P; ++pp) {
        const int ss = pp / K;
        const int tt = pp % K;
#pragma unroll
        for (int mt = 0; mt < 4; ++mt) {
            const int row = wl * 64 + mt * 16 + lan15 + tt * DIL;
            const f16x8 a = *(const f16x8*)(smem + row * RSTR + ss * 64 + kgB);
#pragma unroll
            for (int nt = 0; nt < NT; ++nt) {
                // swapped operands: D rows = co, cols = l
                acc[mt][nt] = __builtin_amdgcn_mfma_f32_16x16x32_f16(brbuf[pp & 1][nt], a, acc[mt][nt], 0, 0, 0);
            }
        }
        if (pp + 2 < P) loadB(pp + 2, brbuf[pp & 1]);   // WAR-safe: after reads
    }

    // ---- epilogue: z -> LDS (b64 scatter, 4 consecutive co/lane) ----
    __syncthreads();   // all staging reads done before smem reuse
    _Float16* zl = (_Float16*)smem;
#pragma unroll
    for (int nt = 0; nt < NT; ++nt) {
        const int co0 = (wc * NT + nt) * 16 + (lane >> 4) * 4;
        const float4 g4 = *(const float4*)&bnp[co0];
        const float4 b4 = *(const float4*)&bnp[COUT + co0];
        const float4 m4 = *(const float4*)&bnp[2 * COUT + co0];
        const float4 v4 = *(const float4*)&bnp[3 * COUT + co0];
        const float4 bi = *(const float4*)&bias[co0];
        float sc[4], sh[4];
        sc[0] = g4.x * rsqrtf(v4.x + 1e-5f); sh[0] = fmaf(bi.x - m4.x, sc[0], b4.x);
        sc[1] = g4.y * rsqrtf(v4.y + 1e-5f); sh[1] = fmaf(bi.y - m4.y, sc[1], b4.y);
        sc[2] = g4.z * rsqrtf(v4.z + 1e-5f); sh[2] = fmaf(bi.z - m4.z, sc[2], b4.z);
        sc[3] = g4.w * rsqrtf(v4.w + 1e-5f); sh[3] = fmaf(bi.w - m4.w, sc[3], b4.w);
#pragma unroll
        for (int mt = 0; mt < 4; ++mt) {
            const int l_loc = wl * 64 + mt * 16 + lan15;
            __align__(8) _Float16 h4[4];
#pragma unroll
            for (int r = 0; r < 4; ++r)
                h4[r] = (_Float16)fmaf(acc[mt][nt][r], sc[r], sh[r]);
            *(int2*)&zl[l_loc * ESTR + co0] = *(const int2*)h4;
        }
    }
    __syncthreads();

    // ---- coalesced sweep ----
    constexpr int CO8 = COUT / 8;
    constexpr int LG  = (CO8 == 16) ? 4 : (CO8 == 8) ? 3 : 2;
    constexpr int RPI = 64 / CO8;
    const int co = (lane & (CO8 - 1)) * 8;

    float ps[8];
#pragma unroll
    for (int j = 0; j < 8; ++j) ps[j] = 0.f;

#pragma unroll
    for (int s2 = 0; s2 < CO8 / 2; ++s2) {
        const int l = w * 32 + s2 * RPI + (lane >> LG);
        _Float16 z8[8];
        *(int4*)z8 = *(const int4*)&zl[l * ESTR + co];
        const size_t gidx = (bL + l0 + l) * COUT + co;
        if constexpr (MODE == 0) {
            __align__(16) _Float16 o8[8];
#pragma unroll
            for (int j = 0; j < 8; ++j) o8[j] = (_Float16)silu_f((float)z8[j]);
            *(int4*)(out + gidx) = *(const int4*)o8;
        } else if constexpr (MODE == 1) {
            _Float16 g8[8];
            *(int4*)g8 = *(const int4*)(aux + gidx);
            __align__(16) _Float16 o8[8];
#pragma unroll
            for (int j = 0; j < 8; ++j) o8[j] = (_Float16)((float)g8[j] * sigm_f((float)z8[j]));
            *(int4*)(out + gidx) = *(const int4*)o8;
        } else {
            _Float16 a8[8];
            *(int4*)a8 = *(const int4*)(aux + gidx);
#pragma unroll
            for (int j = 0; j < 8; ++j) ps[j] += silu_f((float)z8[j] + (float)a8[j]);
        }
    }

    if constexpr (MODE == 3) {
#pragma unroll
        for (int j = 0; j < 8; ++j) {
#pragma unroll
            for (int m = CO8; m < 64; m <<= 1)
                ps[j] += __shfl_xor(ps[j], m, 64);
        }
        if (lane < CO8) {
#pragma unroll
            for (int j = 0; j < 8; ++j) pf[w][co + j] = ps[j];
        }
        __syncthreads();
        if (tid < COUT) {
            const float s = pf[0][tid] + pf[1][tid] + pf[2][tid] + pf[3][tid];
            atomicAdd(&gsum[b * COUT + tid], s);
        }
    }
}

// ============================================================================
// 4-qubit statevector circuit, one thread per batch row
// ============================================================================
template <int BW> DEV void g_ry(float (&re)[16], float (&im)[16], float t) {
    float s, c; sincosf(0.5f * t, &s, &c);
#pragma unroll
    for (int i = 0; i < 16; ++i)
        if (!(i & BW)) {
            const int j = i | BW;
            float r0 = re[i], q0 = im[i], r1 = re[j], q1 = im[j];
            re[i] = c * r0 - s * r1; im[i] = c * q0 - s * q1;
            re[j] = s * r0 + c * r1; im[j] = s * q0 + c * q1;
        }
}
template <int BW> DEV void g_rz(float (&re)[16], float (&im)[16], float t) {
    float s, c; sincosf(0.5f * t, &s, &c);
#pragma unroll
    for (int i = 0; i < 16; ++i) {
        float r = re[i], q = im[i];
        if (i & BW) { re[i] = r * c - q * s; im[i] = q * c + r * s; }
        else        { re[i] = r * c + q * s; im[i] = q * c - r * s; }
    }
}
template <int BC, int BT> DEV void g_cnot(float (&re)[16], float (&im)[16]) {
#pragma unroll
    for (int i = 0; i < 16; ++i)
        if ((i & BC) && !(i & BT)) {
            const int j = i | BT;
            float r = re[i]; re[i] = re[j]; re[j] = r;
            float q = im[i]; im[i] = im[j]; im[j] = q;
        }
}

__global__ void quantum_k(const float* __restrict__ gsum, const float* __restrict__ Wfm,
                          const float* __restrict__ bfm, const float* __restrict__ qw,
                          float* __restrict__ q, int B)
{
    const int b = blockIdx.x * blockDim.x + threadIdx.x;
    if (b >= B) return;

    float qin[4];
#pragma unroll
    for (int j = 0; j < 4; ++j) qin[j] = bfm[j];
    const float inv = 1.f / (float)L_LEN;
    for (int c = 0; c < 128; ++c) {
        const float gv = gsum[b * 128 + c] * inv;
#pragma unroll
        for (int j = 0; j < 4; ++j) qin[j] = fmaf(gv, Wfm[j * 128 + c], qin[j]);
    }

    float re[16], im[16];
#pragma unroll
    for (int i = 0; i < 16; ++i) { re[i] = 0.f; im[i] = 0.f; }
    re[0] = 1.f;

    g_ry<8>(re, im, qin[0]); g_ry<4>(re, im, qin[1]); g_ry<2>(re, im, qin[2]); g_ry<1>(re, im, qin[3]);
    g_rz<8>(re, im, qw[0]);  g_ry<8>(re, im, qw[1]);
    g_rz<4>(re, im, qw[2]);  g_ry<4>(re, im, qw[3]);
    g_rz<2>(re, im, qw[4]);  g_ry<2>(re, im, qw[5]);
    g_rz<1>(re, im, qw[6]);  g_ry<1>(re, im, qw[7]);
    g_cnot<8, 4>(re, im); g_cnot<4, 2>(re, im); g_cnot<2, 1>(re, im);
    g_rz<8>(re, im, qw[8]);  g_ry<8>(re, im, qw[9]);
    g_rz<4>(re, im, qw[10]); g_ry<4>(re, im, qw[11]);
    g_rz<2>(re, im, qw[12]); g_ry<2>(re, im, qw[13]);
    g_rz<1>(re, im, qw[14]); g_ry<1>(re, im, qw[15]);

    float pr[16];
#pragma unroll
    for (int i = 0; i < 16; ++i) pr[i] = re[i] * re[i] + im[i] * im[i];
#pragma unroll
    for (int w = 0; w < 4; ++w) {
        const int bw = 8 >> w;
        float e = 0.f;
#pragma unroll
        for (int i = 0; i < 16; ++i) e += (i & bw) ? -pr[i] : pr[i];
        q[b * 4 + w] = e;
    }
}

// ============================================================================
// FC head: 4 -> 64 -> 32 -> 1
// ============================================================================
__global__ void head_k(const float* __restrict__ q,
                       const float* __restrict__ Wf1, const float* __restrict__ bf1, const float* __restrict__ bnf1,
                       const float* __restrict__ Wf2, const float* __restrict__ bf2, const float* __restrict__ bnf2,
                       const float* __restrict__ Wf3, const float* __restrict__ bf3,
                       float* __restrict__ out)
{
    const int b = blockIdx.x, t = threadIdx.x;
    __shared__ float qs[4], x1[64], x2[32];
    if (t < 4) qs[t] = q[b * 4 + t];
    __syncthreads();
    {
        float a = bf1[t];
#pragma unroll
        for (int k = 0; k < 4; ++k) a = fmaf(qs[k], Wf1[t * 4 + k], a);
        const float sc = bnf1[t] / sqrtf(bnf1[192 + t] + 1e-5f);
        const float z  = (a - bnf1[128 + t]) * sc + bnf1[64 + t];
        x1[t] = silu_f(z);
    }
    __syncthreads();
    if (t < 32) {
        float a = bf2[t];
        for (int k = 0; k < 64; ++k) a = fmaf(x1[k], Wf2[t * 64 + k], a);
        const float sc = bnf2[t] / sqrtf(bnf2[96 + t] + 1e-5f);
        const float z  = (a - bnf2[64 + t]) * sc + bnf2[32 + t];
        x2[t] = silu_f(z);
    }
    __syncthreads();
    if (t == 0) {
        float a = bf3[0];
        for (int k = 0; k < 32; ++k) a = fmaf(x2[k], Wf3[k], a);
        out[b] = a;
    }
}

// ============================================================================
extern "C" void kernel_launch(void* const* d_in, const int* in_sizes, int n_in,
                              void* d_out, int out_size, void* d_ws, size_t ws_size,
                              hipStream_t stream)
{
    (void)n_in; (void)out_size;
    const float* x    = (const float*)d_in[0];
    const float* W1   = (const float*)d_in[1];
    const float* b1   = (const float*)d_in[2];
    const float* bn1  = (const float*)d_in[3];
    const float* Wa1  = (const float*)d_in[4];
    const float* ba1  = (const float*)d_in[5];
    const float* bna1 = (const float*)d_in[6];
    const float* Wa2  = (const float*)d_in[7];
    const float* ba2  = (const float*)d_in[8];
    const float* bna2 = (const float*)d_in[9];
    const float* Wd1  = (const float*)d_in[10];
    const float* bdd1 = (const float*)d_in[11];
    const float* bnd1 = (const float*)d_in[12];
    const float* Wd2  = (const float*)d_in[13];
    const float* bdd2 = (const float*)d_in[14];
    const float* bnd2 = (const float*)d_in[15];
    const float* Wr1  = (const float*)d_in[16];
    const float* br1  = (const float*)d_in[17];
    const float* bnr1 = (const float*)d_in[18];
    const float* Wr2  = (const float*)d_in[19];
    const float* br2  = (const float*)d_in[20];
    const float* bnr2 = (const float*)d_in[21];
    const float* Wfm  = (const float*)d_in[22];
    const float* bfm  = (const float*)d_in[23];
    const float* qw   = (const float*)d_in[24];
    const float* Wf1  = (const float*)d_in[25];
    const float* bf1  = (const float*)d_in[26];
    const float* bnf1 = (const float*)d_in[27];
    const float* Wf2  = (const float*)d_in[28];
    const float* bf2  = (const float*)d_in[29];
    const float* bnf2 = (const float*)d_in[30];
    const float* Wf3  = (const float*)d_in[31];
    const float* bf3  = (const float*)d_in[32];

    const int B = in_sizes[0] / L_LEN;  // 128

    char* base = (char*)d_ws;
    size_t off = 0;
    auto alloc = [&](size_t bytes) -> char* {
        off = (off + 255) & ~(size_t)255;
        char* p = base + off;
        off += bytes;
        return p;
    };

    float* gbuf  = (float*)alloc((size_t)B * 128 * 4);
    float* qbuf  = (float*)alloc((size_t)B * 4 * 4);
    float* zpage = (float*)alloc(256);

    auto wfrag = [&](int cin, int cout, int k) -> _Float16* {
        return (_Float16*)alloc((size_t)k * cout * cin * 2);   // single plane
    };
    _Float16* wa1f = wfrag(64, 32, 7);
    _Float16* wa2f = wfrag(32, 64, 7);
    _Float16* wd1f = wfrag(64, 128, 3);
    _Float16* wd2f = wfrag(128, 128, 3);
    _Float16* wr1f = wfrag(128, 128, 3);
    _Float16* wr2f = wfrag(128, 128, 3);

    const size_t fixed = (off + 255) & ~(size_t)255;
    const size_t PS = (size_t)2 * L_LEN * (64 + 32 + 128 + 128);  // fp16 planes
    size_t avail = (ws_size > fixed + 4096) ? ws_size - fixed - 4096 : 0;
    int chunk = B;
    while (chunk > 1 && (size_t)chunk * PS > avail) chunk >>= 1;

    auto aplane = [&](int C, int c) -> _Float16* {
        return (_Float16*)alloc((size_t)c * L_LEN * C * 2);
    };
    _Float16* h0 = aplane(64,  chunk);
    _Float16* a1 = aplane(32,  chunk);
    _Float16* d1 = aplane(128, chunk);   // also reused for r1
    _Float16* d2 = aplane(128, chunk);
    _Float16* r1 = d1;

    auto pg = [](int tot) { return dim3((tot + 255) / 256); };
    prep_w_k<64, 32, 7>  <<<pg(2*7*2*64),  dim3(256), 0, stream>>>(Wa1, wa1f);
    prep_w_k<32, 64, 7>  <<<pg(1*7*4*64),  dim3(256), 0, stream>>>(Wa2, wa2f);
    prep_w_k<64, 128, 3> <<<pg(2*3*8*64),  dim3(256), 0, stream>>>(Wd1, wd1f);
    prep_w_k<128, 128, 3><<<pg(4*3*8*64),  dim3(256), 0, stream>>>(Wd2, wd2f);
    prep_w_k<128, 128, 3><<<pg(4*3*8*64),  dim3(256), 0, stream>>>(Wr1, wr1f);
    prep_w_k<128, 128, 3><<<pg(4*3*8*64),  dim3(256), 0, stream>>>(Wr2, wr2f);

    hipMemsetAsync(gbuf, 0, (size_t)B * 128 * sizeof(float), stream);
    hipMemsetAsync(zpage, 0, 256, stream);

    const dim3 blk(256);
    for (int sft = 0; sft < B; sft += chunk) {
        const int c = (chunk < B - sft) ? chunk : (B - sft);
        const dim3 cg(L_LEN / 128, 1, c);
        conv1_k<<<dim3(64, c), blk, 0, stream>>>(x + (size_t)sft * L_LEN, W1, b1, bn1, h0);
        conv_mfma_k<64, 32, 7, 1, 0><<<cg, blk, 0, stream>>>(h0, wa1f, ba1, bna1, nullptr, a1, nullptr, zpage);
        conv_mfma_k<32, 64, 7, 1, 1><<<cg, blk, 0, stream>>>(a1, wa2f, ba2, bna2, h0, h0, nullptr, zpage);
        conv_mfma_k<64, 128, 3, 2, 0><<<cg, blk, 0, stream>>>(h0, wd1f, bdd1, bnd1, nullptr, d1, nullptr, zpage);
        conv_mfma_k<128, 128, 3, 4, 0><<<cg, blk, 0, stream>>>(d1, wd2f, bdd2, bnd2, nullptr, d2, nullptr, zpage);
        conv_mfma_k<128, 128, 3, 1, 0><<<cg, blk, 0, stream>>>(d2, wr1f, br1, bnr1, nullptr, r1, nullptr, zpage);
        conv_mfma_k<128, 128, 3, 1, 3><<<cg, blk, 0, stream>>>(r1, wr2f, br2, bnr2, d2, nullptr, gbuf + (size_t)sft * 128, zpage);
    }

    quantum_k<<<dim3((B + 127) / 128), dim3(128), 0, stream>>>(gbuf, Wfm, bfm, qw, qbuf, B);
    head_k<<<dim3(B), dim3(64), 0, stream>>>(qbuf, Wf1, bf1, bnf1, Wf2, bf2, bnf2, Wf3, bf3, (float*)d_out);
}